// Round 17
// baseline (124.827 us; speedup 1.0000x reference)
//
#include <hip/hip_runtime.h>

constexpr int kB = 256;
constexpr int kNC = 99;
constexpr int kN = 100;
constexpr int kC = 128;
constexpr int kH = 512;
constexpr int kL = 3;
constexpr int kNT = kB * kN;   // 25600
constexpr int kRT = 64;        // k_ff rows per block (4 x 16-row MFMA tiles)
constexpr int kFFBlocks = kNT / kRT;   // 400, exact
constexpr float kEps = 1e-5f;

typedef unsigned short u16;
typedef unsigned int u32;
typedef __attribute__((ext_vector_type(8))) __bf16 bf16x8;
typedef __attribute__((ext_vector_type(4))) float f32x4;
typedef __attribute__((ext_vector_type(8))) unsigned short u16x8;

__device__ __forceinline__ u16 f2bf(float x) {
  __bf16 h = (__bf16)x;                 // native v_cvt (RNE)
  return __builtin_bit_cast(u16, h);
}
__device__ __forceinline__ float bf2f(u16 h) {
  union { u32 u; float f; } v; v.u = ((u32)h) << 16;
  return v.f;
}

// per-channel BN affine from raw (sum, sumsq) stats; stats==nullptr -> identity
__device__ __forceinline__ void affine_from_stats(
    const float* __restrict__ stats, const float* __restrict__ gamma,
    const float* __restrict__ beta, int c, float& sc, float& sh) {
  if (stats != nullptr) {
    float s = stats[c], sq = stats[kC + c];
    float m = s * (1.0f / kNT);
    float v = sq * (1.0f / kNT) - m * m;
    float rs = rsqrtf(v + kEps);
    sc = gamma[c] * rs;
    sh = beta[c] - m * sc;
  } else {
    sc = 1.0f;
    sh = 0.0f;
  }
}

// pack one float4-group g (g < 110592) of {gcn_W, W1, W2} into frag layout.
// frag f; lane l; elem j: B[kb*32 + (l>>4)*8 + j][nb*16 + (l&15)]
//   gcn/W1: f = nb*4 + kb ; W2: f = nb*16 + kb
__device__ __forceinline__ void pack_group(
    int g, const float* __restrict__ gcnW, const float* __restrict__ W1,
    const float* __restrict__ W2, u16* __restrict__ wpack) {
  int layer = g / 36864, r = g % 36864;
  const float* src; int shf; u16* base; int isW2 = 0;
  if (r < 4096) {
    src = gcnW + (size_t)layer * kC * kC; shf = 7;
    base = wpack + (size_t)(layer * 288 + 0) * 512;
  } else if (r < 20480) {
    src = W1 + (size_t)layer * kC * kH; shf = 9;
    base = wpack + (size_t)(layer * 288 + 32) * 512; r -= 4096;
  } else {
    src = W2 + (size_t)layer * kH * kC; shf = 7;
    base = wpack + (size_t)(layer * 288 + 160) * 512; r -= 20480; isW2 = 1;
  }
  int e4 = r * 4;
  int k = e4 >> shf, n0 = e4 & ((1 << shf) - 1);
  float4 v = *(const float4*)(src + ((size_t)k << shf) + n0);
  float vv[4] = {v.x, v.y, v.z, v.w};
  int kb = k >> 5, hi = (k >> 3) & 3, j = k & 7;
#pragma unroll
  for (int t = 0; t < 4; ++t) {
    int n = n0 + t;
    int nb = n >> 4, l = hi * 16 + (n & 15);
    int f = isW2 ? (nb * 16 + kb) : (nb * 4 + kb);
    base[(size_t)f * 512 + l * 8 + j] = f2bf(vv[t]);
  }
}

// ---- fused GCN layer, channel-split: 2 blocks per graph, 64 output channels
// each, 256 threads (4 waves), 4 blocks/CU (xs and hs UNION one LDS buffer).
// Residual: bf16 loaded EARLY from global (latency hidden under MFMA),
// affine applied in f32 at use -> single-rounding numerics.
template <bool FIRST>
__global__ __launch_bounds__(256, 4) void k_gcn(
    const u16* __restrict__ yprev, const float* __restrict__ stats_prev,
    const float* __restrict__ gamma_p, const float* __restrict__ beta_p,
    const u16* __restrict__ Wgp, const float* __restrict__ gb,
    float* __restrict__ stats_out, u16* __restrict__ yA,
    const float* __restrict__ dxy, const float* __restrict__ cxy,
    const float* __restrict__ dem, const float* __restrict__ Wd,
    const float* __restrict__ bd, const float* __restrict__ Wi,
    const float* __restrict__ bi, const float* __restrict__ gcnW,
    const float* __restrict__ W1, const float* __restrict__ W2,
    u16* __restrict__ wpack) {
  __shared__ float s_scale[kC], s_shift[kC];
  __shared__ __align__(16) u16 ubuf[112 * 136];   // 30.5 KB: xs, then hs
  __shared__ float sP[4][64], s_sum[64], s_sq[64];
  __shared__ float scoord[kN][4];    // FIRST only
  __shared__ float swt[7][kC];       // FIRST only
  u16 (*xs)[136] = (u16(*)[136])ubuf;
  float* hs = (float*)ubuf;          // stride 68 floats (reused after barrier)
  const int tid = threadIdx.x;
  const int b = blockIdx.x >> 1, half = blockIdx.x & 1;
  const int wave = tid >> 6, lane = tid & 63;
  const int arow = lane & 15, kofs = (lane >> 4) * 8;
  const int crow = (lane >> 4) * 4, ccol = lane & 15;
  const int nbW = half * 4 + wave;
  // prefix-phase identity (also used for early residual loads)
  const int c = tid & 63, jh = tid >> 6;
  const int ch = half * 64 + c;
  const int j0 = jh * 25;
  // B-frags: FIRST loads strided from raw gcn_W layer 0; others load packed.
  bf16x8 bfr[4];
  if (FIRST) {
#pragma unroll
    for (int kb = 0; kb < 4; ++kb)
#pragma unroll
      for (int e = 0; e < 8; ++e) {
        int krow = kb * 32 + (lane >> 4) * 8 + e;
        bfr[kb][e] = (__bf16)gcnW[(size_t)krow * kC + nbW * 16 + (lane & 15)];
      }
  } else {
#pragma unroll
    for (int kb = 0; kb < 4; ++kb)
      bfr[kb] = *(const bf16x8*)(Wgp + (size_t)(nbW * 4 + kb) * 512 + lane * 8);
  }
  if (FIRST) {
    // fold the weight pack into this kernel: one float4-group per thread
    int g = blockIdx.x * 256 + tid;
    if (g < kL * 36864) pack_group(g, gcnW, W1, W2, wpack);
    if (tid < kN) {
      if (tid == 0) {
        scoord[0][0] = dxy[b * 2];
        scoord[0][1] = dxy[b * 2 + 1];
        scoord[0][2] = 0.0f;
      } else {
        int q = b * kNC + tid - 1;
        scoord[tid][0] = cxy[q * 2];
        scoord[tid][1] = cxy[q * 2 + 1];
        scoord[tid][2] = dem[q];
      }
    }
    if (tid < 224) {
      int f = tid * 4, r = f >> 7, c2 = f & 127;
      const float* s;
      switch (r) {
        case 0: s = Wd + c2; break;
        case 1: s = Wd + kC + c2; break;
        case 2: s = bd + c2; break;
        case 3: s = Wi + c2; break;
        case 4: s = Wi + kC + c2; break;
        case 5: s = Wi + 2 * kC + c2; break;
        default: s = bi + c2; break;
      }
      *(float4*)&swt[r][c2] = *(const float4*)s;
    }
  }
  if (tid < kC) affine_from_stats(stats_prev, gamma_p, beta_p, tid,
                                  s_scale[tid], s_shift[tid]);
  if (tid < 64) { s_sum[tid] = 0.0f; s_sq[tid] = 0.0f; }
  __syncthreads();
  const size_t gbase = (size_t)b * kN * kC;
  // EARLY residual loads (global bf16, prefix mapping) — latency hides under
  // staging + MFMA. FIRST recomputes from coords instead (no global read).
  u16 resid[25];
  if (!FIRST) {
#pragma unroll
    for (int jj = 0; jj < 25; ++jj)
      resid[jj] = yprev[gbase + (size_t)(j0 + jj) * kC + ch];
  }
  // stage x (BN-affined, bf16) into LDS: 1792 8-channel (16B) groups, 7 iters
#pragma unroll
  for (int i = 0; i < 7; ++i) {
    int li = i * 256 + tid;
    int lr = li >> 4, lc8 = (li & 15) * 8;
    u16x8 o = {0, 0, 0, 0, 0, 0, 0, 0};
    if (lr < kN) {
      if (FIRST) {
        float sx = scoord[lr][0], sy = scoord[lr][1], sd = scoord[lr][2];
#pragma unroll
        for (int e = 0; e < 8; ++e) {
          int cc = lc8 + e;
          float g = (lr == 0)
              ? fmaf(sx, swt[0][cc], fmaf(sy, swt[1][cc], swt[2][cc]))
              : fmaf(sx, swt[3][cc], fmaf(sy, swt[4][cc], fmaf(sd, swt[5][cc], swt[6][cc])));
          o[e] = f2bf(fmaf(g, s_scale[cc], s_shift[cc]));
        }
      } else {
        u16x8 hv = *(const u16x8*)(yprev + gbase + (size_t)lr * kC + lc8);
#pragma unroll
        for (int e = 0; e < 8; ++e)
          o[e] = f2bf(fmaf(bf2f(hv[e]), s_scale[lc8 + e], s_shift[lc8 + e]));
      }
    }
    *(u16x8*)&xs[lr][lc8] = o;
  }
  __syncthreads();
  // MFMA into registers: wave w owns global col block nbW over all 7 row tiles
  f32x4 acc[7];
#pragma unroll
  for (int t = 0; t < 7; ++t) {
    acc[t] = {0.f, 0.f, 0.f, 0.f};
#pragma unroll
    for (int kb = 0; kb < 4; ++kb) {
      bf16x8 a = *(const bf16x8*)&xs[t * 16 + arow][kb * 32 + kofs];
      acc[t] = __builtin_amdgcn_mfma_f32_16x16x32_bf16(a, bfr[kb], acc[t], 0, 0, 0);
    }
  }
  __syncthreads();   // all xs reads complete -> reuse buffer as hs
#pragma unroll
  for (int t = 0; t < 7; ++t) {
    int rbase = t * 16 + crow;
#pragma unroll
    for (int r = 0; r < 4; ++r)
      if (rbase + r < kN) hs[(rbase + r) * 68 + wave * 16 + ccol] = acc[t][r];
  }
  __syncthreads();
  // prefix over j (4-way split) for owned 64 channels
  const float sc = s_scale[ch], sh = s_shift[ch];
  const float gbc = gb[ch];
  float p = 0.0f;
#pragma unroll
  for (int jj = 0; jj < 25; ++jj)
    p = fmaf(hs[(j0 + jj) * 68 + c], rsqrtf((float)(j0 + jj + 1)), p);
  sP[jh][c] = p;
  __syncthreads();
  float s = 0.0f;
  for (int q = 0; q < jh; ++q) s += sP[q][c];
  float wv0 = 0.f, wv1 = 0.f, wv2 = 0.f, wv3 = 0.f, wd0 = 0.f, wd1 = 0.f, wd2 = 0.f;
  if (FIRST) {
    wv0 = swt[3][ch]; wv1 = swt[4][ch]; wv2 = swt[5][ch]; wv3 = swt[6][ch];
    wd0 = swt[0][ch]; wd1 = swt[1][ch]; wd2 = swt[2][ch];
  }
  float lsum = 0.0f, lsq = 0.0f;
#pragma unroll
  for (int jj = 0; jj < 25; ++jj) {
    int j = j0 + jj;
    float r = rsqrtf((float)(j + 1));
    s = fmaf(hs[j * 68 + c], r, s);
    float xv;
    if (FIRST) {
      float sx = scoord[j][0], sy = scoord[j][1], sd = scoord[j][2];
      xv = (j == 0) ? fmaf(sx, wd0, fmaf(sy, wd1, wd2))
                    : fmaf(sx, wv0, fmaf(sy, wv1, fmaf(sd, wv2, wv3)));
    } else {
      xv = fmaf(bf2f(resid[jj]), sc, sh);   // single rounding (f32 affine)
    }
    float yv = xv + fmaf(s, r, gbc);
    yA[gbase + (size_t)j * kC + ch] = f2bf(yv);
    lsum += yv;
    lsq = fmaf(yv, yv, lsq);
  }
  atomicAdd(&s_sum[c], lsum);
  atomicAdd(&s_sq[c], lsq);
  __syncthreads();
  if (tid < 64) {
    atomicAdd(&stats_out[half * 64 + tid], s_sum[tid]);
    atomicAdd(&stats_out[kC + half * 64 + tid], s_sq[tid]);
  }
}

// fused FF (MFMA bf16): 64-row tile, 400 blocks, 8 waves, 2 H-chunks of 256.
// xs stays live all phase -> residual read directly from LDS at epilogue.
template <bool LAST>
__global__ __launch_bounds__(512, 4) void k_ff(
    const u16* __restrict__ yA, const float* __restrict__ stats_in,
    const float* __restrict__ gamma, const float* __restrict__ beta,
    const u16* __restrict__ W1p, const float* __restrict__ b1,
    const u16* __restrict__ W2p, const float* __restrict__ b2,
    float* __restrict__ stats_out, u16* __restrict__ yB16,
    float* __restrict__ yB32) {
  __shared__ float s_scale[kC], s_shift[kC], s_sum[kC], s_sq[kC];
  __shared__ float s_b1[kH];
  __shared__ u16 xs[kRT][136];       // 17.4 KB (live whole phase)
  __shared__ u16 hid[kRT][272];      // 34.8 KB (one 256-H chunk)
  const int tid = threadIdx.x;
  const int wave = tid >> 6, lane = tid & 63;
  const int arow = lane & 15, kofs = (lane >> 4) * 8;
  const int crow = (lane >> 4) * 4, ccol = lane & 15;
  if (tid < kC) {
    affine_from_stats(stats_in, gamma, beta, tid, s_scale[tid], s_shift[tid]);
    s_sum[tid] = 0.0f;
    s_sq[tid] = 0.0f;
  }
  if (tid < 128) ((float4*)s_b1)[tid] = ((const float4*)b1)[tid];
  __syncthreads();
  const int rb = blockIdx.x * kRT;
  // stage: 1024 8-channel groups (16B loads), 2 iters
#pragma unroll
  for (int i = 0; i < 2; ++i) {
    int li = i * 512 + tid;
    int lr = li >> 4, lc8 = (li & 15) * 8;
    u16x8 hv = *(const u16x8*)(yA + (size_t)(rb + lr) * kC + lc8);
    u16x8 o;
#pragma unroll
    for (int e = 0; e < 8; ++e)
      o[e] = f2bf(fmaf(bf2f(hv[e]), s_scale[lc8 + e], s_shift[lc8 + e]));
    *(u16x8*)&xs[lr][lc8] = o;
  }
  __syncthreads();

  const int c = wave * 16 + ccol;
  f32x4 oacc[4] = {{0.f, 0.f, 0.f, 0.f}, {0.f, 0.f, 0.f, 0.f},
                   {0.f, 0.f, 0.f, 0.f}, {0.f, 0.f, 0.f, 0.f}};
  for (int chk = 0; chk < 2; ++chk) {
    // phase-2 B-frags for this chunk issued early (land during phase 1)
    bf16x8 bw[8];
#pragma unroll
    for (int kk = 0; kk < 8; ++kk)
      bw[kk] = *(const bf16x8*)(W2p + (size_t)(wave * 16 + chk * 8 + kk) * 512 + lane * 8);
    // phase 1: hid[.., 256-chunk] = relu(xs @ W1[:, chunk] + b1)
#pragma unroll
    for (int q = 0; q < 2; ++q) {
      const int nb = chk * 16 + wave * 2 + q;
      bf16x8 b1f[4];
#pragma unroll
      for (int kb = 0; kb < 4; ++kb)
        b1f[kb] = *(const bf16x8*)(W1p + (size_t)(nb * 4 + kb) * 512 + lane * 8);
      const int cl = (wave * 2 + q) * 16 + ccol;           // local col in chunk
      const float bbias = s_b1[chk * 256 + cl];
#pragma unroll
      for (int rt = 0; rt < 4; ++rt) {
        f32x4 acc = {0.f, 0.f, 0.f, 0.f};
#pragma unroll
        for (int kb = 0; kb < 4; ++kb) {
          bf16x8 a = *(const bf16x8*)&xs[rt * 16 + arow][kb * 32 + kofs];
          acc = __builtin_amdgcn_mfma_f32_16x16x32_bf16(a, b1f[kb], acc, 0, 0, 0);
        }
#pragma unroll
        for (int r = 0; r < 4; ++r)
          hid[rt * 16 + crow + r][cl] = f2bf(fmaxf(acc[r] + bbias, 0.0f));
      }
    }
    __syncthreads();
    // phase 2: oacc += hid_chunk @ W2[chunk rows][wave's 16 cols]
#pragma unroll
    for (int kk = 0; kk < 8; ++kk) {
#pragma unroll
      for (int rt = 0; rt < 4; ++rt) {
        bf16x8 ha = *(const bf16x8*)&hid[rt * 16 + arow][kk * 32 + kofs];
        oacc[rt] = __builtin_amdgcn_mfma_f32_16x16x32_bf16(ha, bw[kk], oacc[rt], 0, 0, 0);
      }
    }
    __syncthreads();   // before next chunk overwrites hid
  }

  // epilogue: bias + residual (from xs LDS, already affine'd), store, BN stats
  const float bb = b2[c];
  float psum = 0.0f, psq = 0.0f;
#pragma unroll
  for (int rt = 0; rt < 4; ++rt) {
#pragma unroll
    for (int r = 0; r < 4; ++r) {
      int lrow = rt * 16 + crow + r;
      float xv = bf2f(xs[lrow][c]);
      float o = oacc[rt][r] + bb + xv;
      if (LAST)
        yB32[(size_t)(rb + lrow) * kC + c] = o;
      else
        yB16[(size_t)(rb + lrow) * kC + c] = f2bf(o);
      psum += o;
      psq = fmaf(o, o, psq);
    }
  }
  atomicAdd(&s_sum[c], psum);
  atomicAdd(&s_sq[c], psq);
  __syncthreads();
  if (tid < kC) {
    atomicAdd(&stats_out[tid], s_sum[tid]);
    atomicAdd(&stats_out[kC + tid], s_sq[tid]);
  }
}

// final BN apply + nodes out + per-graph mean, 8-way j-split, 1024 threads
__global__ __launch_bounds__(1024) void k_out(
    const float* __restrict__ yB, const float* __restrict__ stats,
    const float* __restrict__ gamma, const float* __restrict__ beta,
    float* __restrict__ out) {
  __shared__ float sP[8][kC];
  const int b = blockIdx.x;
  const int c = threadIdx.x & 127, jh = threadIdx.x >> 7;
  float sc, sh;
  affine_from_stats(stats, gamma, beta, c, sc, sh);
  const int j0 = (jh < 4) ? jh * 13 : 52 + (jh - 4) * 12;
  const int jc = (jh < 4) ? 13 : 12;
  float acc = 0.0f;
  const size_t base = (size_t)b * kN * kC + c;
  for (int jj = 0; jj < jc; ++jj) {
    int j = j0 + jj;
    float xv = fmaf(yB[base + (size_t)j * kC], sc, sh);
    out[base + (size_t)j * kC] = xv;
    acc += xv;
  }
  sP[jh][c] = acc;
  __syncthreads();
  if (jh == 0) {
    float m = 0.0f;
#pragma unroll
    for (int q = 0; q < 8; ++q) m += sP[q][c];
    out[(size_t)kNT * kC + (size_t)b * kC + c] = m * (1.0f / kN);
  }
}

extern "C" void kernel_launch(void* const* d_in, const int* in_sizes, int n_in,
                              void* d_out, int out_size, void* d_ws, size_t ws_size,
                              hipStream_t stream) {
  const float* depot_xy    = (const float*)d_in[0];
  const float* customer_xy = (const float*)d_in[1];
  const float* demand      = (const float*)d_in[2];
  const float* W_depot     = (const float*)d_in[3];
  const float* b_depot     = (const float*)d_in[4];
  const float* W_init      = (const float*)d_in[5];
  const float* b_init      = (const float*)d_in[6];
  const float* gcn_W       = (const float*)d_in[7];
  const float* gcn_b       = (const float*)d_in[8];
  const float* bn_gamma    = (const float*)d_in[9];
  const float* bn_beta     = (const float*)d_in[10];
  const float* ff_W1       = (const float*)d_in[11];
  const float* ff_b1       = (const float*)d_in[12];
  const float* ff_W2       = (const float*)d_in[13];
  const float* ff_b2       = (const float*)d_in[14];

  u16*   yA16  = (u16*)d_ws;                        // NT*kC bf16
  u16*   yB16  = yA16 + (size_t)kNT * kC;           // NT*kC bf16
  float* yB32  = (float*)(yB16 + (size_t)kNT * kC); // NT*kC f32 (last layer)
  float* stats = yB32 + (size_t)kNT * kC;           // 6 x (sum[128], sumsq[128])
  u16*   wpack = (u16*)(stats + kL * 2 * 2 * kC);

  hipMemsetAsync(stats, 0, kL * 2 * 2 * kC * sizeof(float), stream);
  for (int l = 0; l < kL; ++l) {
    const float* sp = (l == 0) ? nullptr : stats + ((l - 1) * 2 + 1) * 2 * kC;
    const float* gp = (l == 0) ? nullptr : bn_gamma + (l - 1) * kC;
    const float* bp = (l == 0) ? nullptr : bn_beta + (l - 1) * kC;
    float* s0 = stats + (l * 2 + 0) * 2 * kC;
    float* s1 = stats + (l * 2 + 1) * 2 * kC;
    const u16* wg  = wpack + (size_t)(l * 288 + 0) * 512;
    const u16* w1p = wpack + (size_t)(l * 288 + 32) * 512;
    const u16* w2p = wpack + (size_t)(l * 288 + 160) * 512;
    if (l == 0) {
      k_gcn<true><<<kB * 2, 256, 0, stream>>>(
          nullptr, sp, gp, bp, nullptr, gcn_b + l * kC, s0, yA16,
          depot_xy, customer_xy, demand, W_depot, b_depot, W_init, b_init,
          gcn_W, ff_W1, ff_W2, wpack);
    } else {
      k_gcn<false><<<kB * 2, 256, 0, stream>>>(
          yB16, sp, gp, bp, wg, gcn_b + l * kC, s0, yA16,
          nullptr, nullptr, nullptr, nullptr, nullptr, nullptr, nullptr,
          nullptr, nullptr, nullptr, nullptr);
    }
    if (l < kL - 1) {
      k_ff<false><<<kFFBlocks, 512, 0, stream>>>(
          yA16, s0, bn_gamma + l * kC, bn_beta + l * kC,
          w1p, ff_b1 + l * kH, w2p, ff_b2 + l * kC, s1, yB16, nullptr);
    } else {
      k_ff<true><<<kFFBlocks, 512, 0, stream>>>(
          yA16, s0, bn_gamma + l * kC, bn_beta + l * kC,
          w1p, ff_b1 + l * kH, w2p, ff_b2 + l * kC, s1, nullptr, yB32);
    }
  }
  k_out<<<kB, 1024, 0, stream>>>(yB32, stats + (2 * 2 + 1) * 2 * kC,
                                 bn_gamma + 2 * kC, bn_beta + 2 * kC, (float*)d_out);
}

// Round 18
// 107.442 us; speedup vs baseline: 1.1618x; 1.1618x over previous
//
#include <hip/hip_runtime.h>

constexpr int kB = 256;
constexpr int kNC = 99;
constexpr int kN = 100;
constexpr int kC = 128;
constexpr int kH = 512;
constexpr int kL = 3;
constexpr int kNT = kB * kN;   // 25600
constexpr int kRT = 64;        // k_ff rows per block (4 x 16-row MFMA tiles)
constexpr int kFFBlocks = kNT / kRT;   // 400, exact
constexpr int kSB = 8;         // stats banks (by blockIdx & 7 -> per-XCD L2)
constexpr float kEps = 1e-5f;

typedef unsigned short u16;
typedef unsigned int u32;
typedef __attribute__((ext_vector_type(8))) __bf16 bf16x8;
typedef __attribute__((ext_vector_type(4))) float f32x4;
typedef __attribute__((ext_vector_type(8))) unsigned short u16x8;

__device__ __forceinline__ u16 f2bf(float x) {
  __bf16 h = (__bf16)x;                 // native v_cvt (RNE)
  return __builtin_bit_cast(u16, h);
}
__device__ __forceinline__ float bf2f(u16 h) {
  union { u32 u; float f; } v; v.u = ((u32)h) << 16;
  return v.f;
}

// per-channel BN affine from 8-way-banked raw (sum, sumsq) stats.
// slot base points at bank 0 of the slot; nullptr -> identity.
__device__ __forceinline__ void affine_from_stats(
    const float* __restrict__ slot, const float* __restrict__ gamma,
    const float* __restrict__ beta, int c, float& sc, float& sh) {
  if (slot != nullptr) {
    float s = 0.0f, sq = 0.0f;
#pragma unroll
    for (int k = 0; k < kSB; ++k) {
      s += slot[k * 2 * kC + c];
      sq += slot[k * 2 * kC + kC + c];
    }
    float m = s * (1.0f / kNT);
    float v = sq * (1.0f / kNT) - m * m;
    float rs = rsqrtf(v + kEps);
    sc = gamma[c] * rs;
    sh = beta[c] - m * sc;
  } else {
    sc = 1.0f;
    sh = 0.0f;
  }
}

// pack one float4-group g (g < 110592) of {gcn_W, W1, W2} into frag layout.
// frag f; lane l; elem j: B[kb*32 + (l>>4)*8 + j][nb*16 + (l&15)]
//   gcn/W1: f = nb*4 + kb ; W2: f = nb*16 + kb
__device__ __forceinline__ void pack_group(
    int g, const float* __restrict__ gcnW, const float* __restrict__ W1,
    const float* __restrict__ W2, u16* __restrict__ wpack) {
  int layer = g / 36864, r = g % 36864;
  const float* src; int shf; u16* base; int isW2 = 0;
  if (r < 4096) {
    src = gcnW + (size_t)layer * kC * kC; shf = 7;
    base = wpack + (size_t)(layer * 288 + 0) * 512;
  } else if (r < 20480) {
    src = W1 + (size_t)layer * kC * kH; shf = 9;
    base = wpack + (size_t)(layer * 288 + 32) * 512; r -= 4096;
  } else {
    src = W2 + (size_t)layer * kH * kC; shf = 7;
    base = wpack + (size_t)(layer * 288 + 160) * 512; r -= 20480; isW2 = 1;
  }
  int e4 = r * 4;
  int k = e4 >> shf, n0 = e4 & ((1 << shf) - 1);
  float4 v = *(const float4*)(src + ((size_t)k << shf) + n0);
  float vv[4] = {v.x, v.y, v.z, v.w};
  int kb = k >> 5, hi = (k >> 3) & 3, j = k & 7;
#pragma unroll
  for (int t = 0; t < 4; ++t) {
    int n = n0 + t;
    int nb = n >> 4, l = hi * 16 + (n & 15);
    int f = isW2 ? (nb * 16 + kb) : (nb * 4 + kb);
    base[(size_t)f * 512 + l * 8 + j] = f2bf(vv[t]);
  }
}

// ---- fused GCN layer, channel-split: 2 blocks per graph, 64 output channels
// each, 256 threads (4 waves), 4 blocks/CU (xs and hs UNION one LDS buffer).
// Residual: bf16 loaded EARLY from global (latency hidden under MFMA),
// affine applied in f32 at use -> single-rounding numerics.
template <bool FIRST>
__global__ __launch_bounds__(256, 4) void k_gcn(
    const u16* __restrict__ yprev, const float* __restrict__ stats_prev,
    const float* __restrict__ gamma_p, const float* __restrict__ beta_p,
    const u16* __restrict__ Wgp, const float* __restrict__ gb,
    float* __restrict__ stats_out, u16* __restrict__ yA,
    const float* __restrict__ dxy, const float* __restrict__ cxy,
    const float* __restrict__ dem, const float* __restrict__ Wd,
    const float* __restrict__ bd, const float* __restrict__ Wi,
    const float* __restrict__ bi, const float* __restrict__ gcnW,
    const float* __restrict__ W1, const float* __restrict__ W2,
    u16* __restrict__ wpack) {
  __shared__ float s_scale[kC], s_shift[kC];
  __shared__ __align__(16) u16 ubuf[112 * 136];   // 30.5 KB: xs, then hs
  __shared__ float sP[4][64], s_sum[64], s_sq[64];
  __shared__ float scoord[kN][4];    // FIRST only
  __shared__ float swt[7][kC];       // FIRST only
  u16 (*xs)[136] = (u16(*)[136])ubuf;
  float* hs = (float*)ubuf;          // stride 68 floats (reused after barrier)
  const int tid = threadIdx.x;
  const int b = blockIdx.x >> 1, half = blockIdx.x & 1;
  const int wave = tid >> 6, lane = tid & 63;
  const int arow = lane & 15, kofs = (lane >> 4) * 8;
  const int crow = (lane >> 4) * 4, ccol = lane & 15;
  const int nbW = half * 4 + wave;
  // prefix-phase identity (also used for early residual loads)
  const int c = tid & 63, jh = tid >> 6;
  const int ch = half * 64 + c;
  const int j0 = jh * 25;
  // B-frags: FIRST loads strided from raw gcn_W layer 0; others load packed.
  bf16x8 bfr[4];
  if (FIRST) {
#pragma unroll
    for (int kb = 0; kb < 4; ++kb)
#pragma unroll
      for (int e = 0; e < 8; ++e) {
        int krow = kb * 32 + (lane >> 4) * 8 + e;
        bfr[kb][e] = (__bf16)gcnW[(size_t)krow * kC + nbW * 16 + (lane & 15)];
      }
  } else {
#pragma unroll
    for (int kb = 0; kb < 4; ++kb)
      bfr[kb] = *(const bf16x8*)(Wgp + (size_t)(nbW * 4 + kb) * 512 + lane * 8);
  }
  if (FIRST) {
    // fold the weight pack into this kernel: one float4-group per thread
    int g = blockIdx.x * 256 + tid;
    if (g < kL * 36864) pack_group(g, gcnW, W1, W2, wpack);
    if (tid < kN) {
      if (tid == 0) {
        scoord[0][0] = dxy[b * 2];
        scoord[0][1] = dxy[b * 2 + 1];
        scoord[0][2] = 0.0f;
      } else {
        int q = b * kNC + tid - 1;
        scoord[tid][0] = cxy[q * 2];
        scoord[tid][1] = cxy[q * 2 + 1];
        scoord[tid][2] = dem[q];
      }
    }
    if (tid < 224) {
      int f = tid * 4, r = f >> 7, c2 = f & 127;
      const float* s;
      switch (r) {
        case 0: s = Wd + c2; break;
        case 1: s = Wd + kC + c2; break;
        case 2: s = bd + c2; break;
        case 3: s = Wi + c2; break;
        case 4: s = Wi + kC + c2; break;
        case 5: s = Wi + 2 * kC + c2; break;
        default: s = bi + c2; break;
      }
      *(float4*)&swt[r][c2] = *(const float4*)s;
    }
  }
  if (tid < kC) affine_from_stats(stats_prev, gamma_p, beta_p, tid,
                                  s_scale[tid], s_shift[tid]);
  if (tid < 64) { s_sum[tid] = 0.0f; s_sq[tid] = 0.0f; }
  __syncthreads();
  const size_t gbase = (size_t)b * kN * kC;
  // EARLY residual loads (global bf16, prefix mapping) — latency hides under
  // staging + MFMA. FIRST recomputes from coords instead (no global read).
  u16 resid[25];
  if (!FIRST) {
#pragma unroll
    for (int jj = 0; jj < 25; ++jj)
      resid[jj] = yprev[gbase + (size_t)(j0 + jj) * kC + ch];
  }
  // stage x (BN-affined, bf16) into LDS: 1792 8-channel (16B) groups, 7 iters
#pragma unroll
  for (int i = 0; i < 7; ++i) {
    int li = i * 256 + tid;
    int lr = li >> 4, lc8 = (li & 15) * 8;
    u16x8 o = {0, 0, 0, 0, 0, 0, 0, 0};
    if (lr < kN) {
      if (FIRST) {
        float sx = scoord[lr][0], sy = scoord[lr][1], sd = scoord[lr][2];
#pragma unroll
        for (int e = 0; e < 8; ++e) {
          int cc = lc8 + e;
          float g = (lr == 0)
              ? fmaf(sx, swt[0][cc], fmaf(sy, swt[1][cc], swt[2][cc]))
              : fmaf(sx, swt[3][cc], fmaf(sy, swt[4][cc], fmaf(sd, swt[5][cc], swt[6][cc])));
          o[e] = f2bf(fmaf(g, s_scale[cc], s_shift[cc]));
        }
      } else {
        u16x8 hv = *(const u16x8*)(yprev + gbase + (size_t)lr * kC + lc8);
#pragma unroll
        for (int e = 0; e < 8; ++e)
          o[e] = f2bf(fmaf(bf2f(hv[e]), s_scale[lc8 + e], s_shift[lc8 + e]));
      }
    }
    *(u16x8*)&xs[lr][lc8] = o;
  }
  __syncthreads();
  // MFMA into registers: wave w owns global col block nbW over all 7 row tiles
  f32x4 acc[7];
#pragma unroll
  for (int t = 0; t < 7; ++t) {
    acc[t] = {0.f, 0.f, 0.f, 0.f};
#pragma unroll
    for (int kb = 0; kb < 4; ++kb) {
      bf16x8 a = *(const bf16x8*)&xs[t * 16 + arow][kb * 32 + kofs];
      acc[t] = __builtin_amdgcn_mfma_f32_16x16x32_bf16(a, bfr[kb], acc[t], 0, 0, 0);
    }
  }
  __syncthreads();   // all xs reads complete -> reuse buffer as hs
#pragma unroll
  for (int t = 0; t < 7; ++t) {
    int rbase = t * 16 + crow;
#pragma unroll
    for (int r = 0; r < 4; ++r)
      if (rbase + r < kN) hs[(rbase + r) * 68 + wave * 16 + ccol] = acc[t][r];
  }
  __syncthreads();
  // prefix over j (4-way split) for owned 64 channels
  const float sc = s_scale[ch], sh = s_shift[ch];
  const float gbc = gb[ch];
  float p = 0.0f;
#pragma unroll
  for (int jj = 0; jj < 25; ++jj)
    p = fmaf(hs[(j0 + jj) * 68 + c], rsqrtf((float)(j0 + jj + 1)), p);
  sP[jh][c] = p;
  __syncthreads();
  float s = 0.0f;
  for (int q = 0; q < jh; ++q) s += sP[q][c];
  float wv0 = 0.f, wv1 = 0.f, wv2 = 0.f, wv3 = 0.f, wd0 = 0.f, wd1 = 0.f, wd2 = 0.f;
  if (FIRST) {
    wv0 = swt[3][ch]; wv1 = swt[4][ch]; wv2 = swt[5][ch]; wv3 = swt[6][ch];
    wd0 = swt[0][ch]; wd1 = swt[1][ch]; wd2 = swt[2][ch];
  }
  float lsum = 0.0f, lsq = 0.0f;
#pragma unroll
  for (int jj = 0; jj < 25; ++jj) {
    int j = j0 + jj;
    float r = rsqrtf((float)(j + 1));
    s = fmaf(hs[j * 68 + c], r, s);
    float xv;
    if (FIRST) {
      float sx = scoord[j][0], sy = scoord[j][1], sd = scoord[j][2];
      xv = (j == 0) ? fmaf(sx, wd0, fmaf(sy, wd1, wd2))
                    : fmaf(sx, wv0, fmaf(sy, wv1, fmaf(sd, wv2, wv3)));
    } else {
      xv = fmaf(bf2f(resid[jj]), sc, sh);   // single rounding (f32 affine)
    }
    float yv = xv + fmaf(s, r, gbc);
    yA[gbase + (size_t)j * kC + ch] = f2bf(yv);
    lsum += yv;
    lsq = fmaf(yv, yv, lsq);
  }
  atomicAdd(&s_sum[c], lsum);
  atomicAdd(&s_sq[c], lsq);
  __syncthreads();
  // banked global stats: chain length 512 -> 64 per address
  float* s0b = stats_out + (size_t)(blockIdx.x & (kSB - 1)) * 2 * kC;
  if (tid < 64) {
    atomicAdd(&s0b[half * 64 + tid], s_sum[tid]);
    atomicAdd(&s0b[kC + half * 64 + tid], s_sq[tid]);
  }
}

// fused FF (MFMA bf16): 64-row tile, 400 blocks, 8 waves, 2 H-chunks of 256.
// xs stays live all phase -> residual read directly from LDS at epilogue.
template <bool LAST>
__global__ __launch_bounds__(512, 4) void k_ff(
    const u16* __restrict__ yA, const float* __restrict__ stats_in,
    const float* __restrict__ gamma, const float* __restrict__ beta,
    const u16* __restrict__ W1p, const float* __restrict__ b1,
    const u16* __restrict__ W2p, const float* __restrict__ b2,
    float* __restrict__ stats_out, u16* __restrict__ yB16,
    float* __restrict__ yB32) {
  __shared__ float s_scale[kC], s_shift[kC], s_sum[kC], s_sq[kC];
  __shared__ float s_b1[kH];
  __shared__ u16 xs[kRT][136];       // 17.4 KB (live whole phase)
  __shared__ u16 hid[kRT][272];      // 34.8 KB (one 256-H chunk)
  const int tid = threadIdx.x;
  const int wave = tid >> 6, lane = tid & 63;
  const int arow = lane & 15, kofs = (lane >> 4) * 8;
  const int crow = (lane >> 4) * 4, ccol = lane & 15;
  if (tid < kC) {
    affine_from_stats(stats_in, gamma, beta, tid, s_scale[tid], s_shift[tid]);
    s_sum[tid] = 0.0f;
    s_sq[tid] = 0.0f;
  }
  if (tid < 128) ((float4*)s_b1)[tid] = ((const float4*)b1)[tid];
  __syncthreads();
  const int rb = blockIdx.x * kRT;
  // stage: 1024 8-channel groups (16B loads), 2 iters
#pragma unroll
  for (int i = 0; i < 2; ++i) {
    int li = i * 512 + tid;
    int lr = li >> 4, lc8 = (li & 15) * 8;
    u16x8 hv = *(const u16x8*)(yA + (size_t)(rb + lr) * kC + lc8);
    u16x8 o;
#pragma unroll
    for (int e = 0; e < 8; ++e)
      o[e] = f2bf(fmaf(bf2f(hv[e]), s_scale[lc8 + e], s_shift[lc8 + e]));
    *(u16x8*)&xs[lr][lc8] = o;
  }
  __syncthreads();

  const int c = wave * 16 + ccol;
  f32x4 oacc[4] = {{0.f, 0.f, 0.f, 0.f}, {0.f, 0.f, 0.f, 0.f},
                   {0.f, 0.f, 0.f, 0.f}, {0.f, 0.f, 0.f, 0.f}};
  for (int chk = 0; chk < 2; ++chk) {
    // phase-2 B-frags for this chunk issued early (land during phase 1)
    bf16x8 bw[8];
#pragma unroll
    for (int kk = 0; kk < 8; ++kk)
      bw[kk] = *(const bf16x8*)(W2p + (size_t)(wave * 16 + chk * 8 + kk) * 512 + lane * 8);
    // phase 1: hid[.., 256-chunk] = relu(xs @ W1[:, chunk] + b1)
#pragma unroll
    for (int q = 0; q < 2; ++q) {
      const int nb = chk * 16 + wave * 2 + q;
      bf16x8 b1f[4];
#pragma unroll
      for (int kb = 0; kb < 4; ++kb)
        b1f[kb] = *(const bf16x8*)(W1p + (size_t)(nb * 4 + kb) * 512 + lane * 8);
      const int cl = (wave * 2 + q) * 16 + ccol;           // local col in chunk
      const float bbias = s_b1[chk * 256 + cl];
#pragma unroll
      for (int rt = 0; rt < 4; ++rt) {
        f32x4 acc = {0.f, 0.f, 0.f, 0.f};
#pragma unroll
        for (int kb = 0; kb < 4; ++kb) {
          bf16x8 a = *(const bf16x8*)&xs[rt * 16 + arow][kb * 32 + kofs];
          acc = __builtin_amdgcn_mfma_f32_16x16x32_bf16(a, b1f[kb], acc, 0, 0, 0);
        }
#pragma unroll
        for (int r = 0; r < 4; ++r)
          hid[rt * 16 + crow + r][cl] = f2bf(fmaxf(acc[r] + bbias, 0.0f));
      }
    }
    __syncthreads();
    // phase 2: oacc += hid_chunk @ W2[chunk rows][wave's 16 cols]
#pragma unroll
    for (int kk = 0; kk < 8; ++kk) {
#pragma unroll
      for (int rt = 0; rt < 4; ++rt) {
        bf16x8 ha = *(const bf16x8*)&hid[rt * 16 + arow][kk * 32 + kofs];
        oacc[rt] = __builtin_amdgcn_mfma_f32_16x16x32_bf16(ha, bw[kk], oacc[rt], 0, 0, 0);
      }
    }
    __syncthreads();   // before next chunk overwrites hid
  }

  // epilogue: bias + residual (from xs LDS, already affine'd), store, BN stats
  const float bb = b2[c];
  float psum = 0.0f, psq = 0.0f;
#pragma unroll
  for (int rt = 0; rt < 4; ++rt) {
#pragma unroll
    for (int r = 0; r < 4; ++r) {
      int lrow = rt * 16 + crow + r;
      float xv = bf2f(xs[lrow][c]);
      float o = oacc[rt][r] + bb + xv;
      if (LAST)
        yB32[(size_t)(rb + lrow) * kC + c] = o;
      else
        yB16[(size_t)(rb + lrow) * kC + c] = f2bf(o);
      psum += o;
      psq = fmaf(o, o, psq);
    }
  }
  atomicAdd(&s_sum[c], psum);
  atomicAdd(&s_sq[c], psq);
  __syncthreads();
  // banked global stats: chain length 400 -> 50 per address
  float* s1b = stats_out + (size_t)(blockIdx.x & (kSB - 1)) * 2 * kC;
  if (tid < kC) {
    atomicAdd(&s1b[tid], s_sum[tid]);
    atomicAdd(&s1b[kC + tid], s_sq[tid]);
  }
}

// final BN apply + nodes out + per-graph mean, 8-way j-split, 1024 threads
__global__ __launch_bounds__(1024) void k_out(
    const float* __restrict__ yB, const float* __restrict__ stats,
    const float* __restrict__ gamma, const float* __restrict__ beta,
    float* __restrict__ out) {
  __shared__ float sP[8][kC];
  const int b = blockIdx.x;
  const int c = threadIdx.x & 127, jh = threadIdx.x >> 7;
  float sc, sh;
  affine_from_stats(stats, gamma, beta, c, sc, sh);
  const int j0 = (jh < 4) ? jh * 13 : 52 + (jh - 4) * 12;
  const int jc = (jh < 4) ? 13 : 12;
  float acc = 0.0f;
  const size_t base = (size_t)b * kN * kC + c;
  for (int jj = 0; jj < jc; ++jj) {
    int j = j0 + jj;
    float xv = fmaf(yB[base + (size_t)j * kC], sc, sh);
    out[base + (size_t)j * kC] = xv;
    acc += xv;
  }
  sP[jh][c] = acc;
  __syncthreads();
  if (jh == 0) {
    float m = 0.0f;
#pragma unroll
    for (int q = 0; q < 8; ++q) m += sP[q][c];
    out[(size_t)kNT * kC + (size_t)b * kC + c] = m * (1.0f / kN);
  }
}

extern "C" void kernel_launch(void* const* d_in, const int* in_sizes, int n_in,
                              void* d_out, int out_size, void* d_ws, size_t ws_size,
                              hipStream_t stream) {
  const float* depot_xy    = (const float*)d_in[0];
  const float* customer_xy = (const float*)d_in[1];
  const float* demand      = (const float*)d_in[2];
  const float* W_depot     = (const float*)d_in[3];
  const float* b_depot     = (const float*)d_in[4];
  const float* W_init      = (const float*)d_in[5];
  const float* b_init      = (const float*)d_in[6];
  const float* gcn_W       = (const float*)d_in[7];
  const float* gcn_b       = (const float*)d_in[8];
  const float* bn_gamma    = (const float*)d_in[9];
  const float* bn_beta     = (const float*)d_in[10];
  const float* ff_W1       = (const float*)d_in[11];
  const float* ff_b1       = (const float*)d_in[12];
  const float* ff_W2       = (const float*)d_in[13];
  const float* ff_b2       = (const float*)d_in[14];

  u16*   yA16  = (u16*)d_ws;                        // NT*kC bf16
  u16*   yB16  = yA16 + (size_t)kNT * kC;           // NT*kC bf16
  float* yB32  = (float*)(yB16 + (size_t)kNT * kC); // NT*kC f32 (last layer)
  float* stats = yB32 + (size_t)kNT * kC;           // 6 slots x 8 banks x (sum,sq)[128]
  u16*   wpack = (u16*)(stats + (size_t)kL * 2 * kSB * 2 * kC);

  hipMemsetAsync(stats, 0, (size_t)kL * 2 * kSB * 2 * kC * sizeof(float), stream);
  auto slot = [&](int idx) { return stats + (size_t)idx * kSB * 2 * kC; };
  for (int l = 0; l < kL; ++l) {
    const float* sp = (l == 0) ? nullptr : slot((l - 1) * 2 + 1);
    const float* gp = (l == 0) ? nullptr : bn_gamma + (l - 1) * kC;
    const float* bp = (l == 0) ? nullptr : bn_beta + (l - 1) * kC;
    float* s0 = slot(l * 2 + 0);
    float* s1 = slot(l * 2 + 1);
    const u16* wg  = wpack + (size_t)(l * 288 + 0) * 512;
    const u16* w1p = wpack + (size_t)(l * 288 + 32) * 512;
    const u16* w2p = wpack + (size_t)(l * 288 + 160) * 512;
    if (l == 0) {
      k_gcn<true><<<kB * 2, 256, 0, stream>>>(
          nullptr, sp, gp, bp, nullptr, gcn_b + l * kC, s0, yA16,
          depot_xy, customer_xy, demand, W_depot, b_depot, W_init, b_init,
          gcn_W, ff_W1, ff_W2, wpack);
    } else {
      k_gcn<false><<<kB * 2, 256, 0, stream>>>(
          yB16, sp, gp, bp, wg, gcn_b + l * kC, s0, yA16,
          nullptr, nullptr, nullptr, nullptr, nullptr, nullptr, nullptr,
          nullptr, nullptr, nullptr, nullptr);
    }
    if (l < kL - 1) {
      k_ff<false><<<kFFBlocks, 512, 0, stream>>>(
          yA16, s0, bn_gamma + l * kC, bn_beta + l * kC,
          w1p, ff_b1 + l * kH, w2p, ff_b2 + l * kC, s1, yB16, nullptr);
    } else {
      k_ff<true><<<kFFBlocks, 512, 0, stream>>>(
          yA16, s0, bn_gamma + l * kC, bn_beta + l * kC,
          w1p, ff_b1 + l * kH, w2p, ff_b2 + l * kC, s1, nullptr, yB32);
    }
  }
  k_out<<<kB, 1024, 0, stream>>>(yB32, slot(2 * 2 + 1),
                                 bn_gamma + 2 * kC, bn_beta + 2 * kC, (float*)d_out);
}